// Round 3
// baseline (581.014 us; speedup 1.0000x reference)
//
#include <hip/hip_runtime.h>
#include <stdint.h>

typedef __bf16 bf16_t;
typedef bf16_t bf16x8 __attribute__((ext_vector_type(8)));
typedef float f32x4 __attribute__((ext_vector_type(4)));

#define N_NODES 8192
#define DIM 512

typedef __attribute__((address_space(1))) void as1_void;
typedef __attribute__((address_space(3))) void as3_void;

// async global -> LDS, 16B per lane. LDS dest = wave-uniform base + lane*16.
__device__ __forceinline__ void gload_lds16(const void* g, void* l) {
  __builtin_amdgcn_global_load_lds((as1_void*)g, (as3_void*)l, 16, 0, 0);
}

// ============================================================================
// k_yw: Yt[n,k] = sum_d W[n,d] * x[k,d]   (Yt = (x @ W^T)^T, [512][8192] bf16)
// 128(n) x 128(k) tile, BK=32, 4 waves (2x2), wave-tile 64x64, acc[4][4].
// fp32 operands staged via global_load_lds, XOR swizzle (phys = log ^ (row&7)
// on 128B rows) applied inversely at the global source, cvt->bf16 at read.
// Conservative __syncthreads double-buffer loop (NIT=16). LDS = 64 KB.
// ============================================================================
__global__ __launch_bounds__(256) void k_yw(const float* __restrict__ x,
                                            const float* __restrict__ W,
                                            bf16_t* __restrict__ Yt) {
  constexpr int NIT = DIM / 32;  // 16
  __shared__ float As[2][128 * 32];  // W rows (n), 16 KB each
  __shared__ float Bs[2][128 * 32];  // x rows (k), 16 KB each

  const int b = blockIdx.x;
  const int n0 = (b & 3) * 128;
  const int k0 = (b >> 2) * 128;

  const int t = threadIdx.x;
  const int lane = t & 63;
  const int w = t >> 6;
  const int wr = w & 1;
  const int wc = w >> 1;
  const int lrow = lane & 15;
  const int quad = lane >> 4;

  const int srow = t >> 3;                      // slot row base
  const int aoff = ((t & 7) ^ (srow & 7)) * 4;  // f32 col, inverse swizzle
  const float* ag = W + (size_t)(n0 + srow) * DIM + aoff;
  const float* bg = x + (size_t)(k0 + srow) * DIM + aoff;

  auto stage = [&](int it, int buf) {
    const int kc = it * 32;
#pragma unroll
    for (int i = 0; i < 4; ++i) {
      gload_lds16(ag + (size_t)(i * 32) * DIM + kc, &As[buf][(i * 256 + t) * 4]);
      gload_lds16(bg + (size_t)(i * 32) * DIM + kc, &Bs[buf][(i * 256 + t) * 4]);
    }
  };

  const int apc0 = ((quad * 2) ^ (lrow & 7)) * 4;
  const int apc1 = (((quad * 2) ^ (lrow & 7)) ^ 1) * 4;

  f32x4 acc[4][4] = {};

  auto compute = [&](int buf) {
    bf16x8 af[4], bfr[4];
#pragma unroll
    for (int ii = 0; ii < 4; ++ii) {
      const int rb = (wr * 64 + ii * 16 + lrow) * 32;
      f32x4 a0 = *(const f32x4*)&As[buf][rb + apc0];
      f32x4 a1 = *(const f32x4*)&As[buf][rb + apc1];
#pragma unroll
      for (int z = 0; z < 4; ++z) {
        af[ii][z] = (bf16_t)a0[z];
        af[ii][z + 4] = (bf16_t)a1[z];
      }
    }
#pragma unroll
    for (int jj = 0; jj < 4; ++jj) {
      const int rb = (wc * 64 + jj * 16 + lrow) * 32;
      f32x4 b0 = *(const f32x4*)&Bs[buf][rb + apc0];
      f32x4 b1 = *(const f32x4*)&Bs[buf][rb + apc1];
#pragma unroll
      for (int z = 0; z < 4; ++z) {
        bfr[jj][z] = (bf16_t)b0[z];
        bfr[jj][z + 4] = (bf16_t)b1[z];
      }
    }
#pragma unroll
    for (int ii = 0; ii < 4; ++ii)
#pragma unroll
      for (int jj = 0; jj < 4; ++jj)
        acc[ii][jj] =
            __builtin_amdgcn_mfma_f32_16x16x32_bf16(af[ii], bfr[jj], acc[ii][jj], 0, 0, 0);
  };

  stage(0, 0);
  __syncthreads();
  int cur = 0;
#pragma unroll 1
  for (int it = 0; it < NIT; ++it) {
    if (it + 1 < NIT) stage(it + 1, cur ^ 1);
    compute(cur);
    __syncthreads();
    cur ^= 1;
  }

#pragma unroll
  for (int ii = 0; ii < 4; ++ii)
#pragma unroll
    for (int jj = 0; jj < 4; ++jj) {
      const int col = k0 + wc * 64 + jj * 16 + lrow;
#pragma unroll
      for (int r = 0; r < 4; ++r) {
        const int row = n0 + wr * 64 + ii * 16 + quad * 4 + r;
        Yt[(size_t)row * N_NODES + col] = (bf16_t)acc[ii][jj][r];
      }
    }
}

// ============================================================================
// k_main: out = relu(adj @ Y + b)  == relu(adj @ x @ W^T + b)
// A = adj [8192x8192] f32 (staged fp32, cvt at read), B = Yt [512][8192] bf16.
// BM=64 x BN=128 tile, BK=32, NIT=256, 4 waves (2x2), wave-tile 32x64,
// acc[2][4]. T3/T4 counted-vmcnt pipeline: 4 LDS stages (16 KB each, 64 KB
// total -> 2 blocks/CU co-resident), lookahead-3 prefetch.
// Per-wave ledger: 4 DMAs/stage, 3 stages in flight = 12 outstanding;
// s_waitcnt vmcnt(8) drains exactly the oldest stage; per-wave lgkmcnt(0)
// before the barrier retires this wave's reads of buf[it-1], so the
// post-barrier stage(it+3) overwrite of that buffer cannot race any reader.
// Barrier is inline-asm s_barrier WITH "memory" clobber (compiler fence --
// the builtin is IntrNoMem and lets stores/DMAs hoist across).
// Grid 512, XCD-swizzled (512 % 8 == 0, bijective).
// ============================================================================
__global__ __launch_bounds__(256) void k_main(const float* __restrict__ A,
                                              const bf16_t* __restrict__ Bt,
                                              const float* __restrict__ bias,
                                              float* __restrict__ out) {
  constexpr int K = N_NODES;
  constexpr int NIT = K / 32;  // 256
  __shared__ float As[4][64 * 32];    // 32 KB
  __shared__ bf16_t Bs[4][128 * 32];  // 32 KB

  const int b = blockIdx.x;
  const int xcd = b & 7;
  const int i6 = b >> 3;       // 0..63
  const int n_tile = i6 & 3;
  const int mg = i6 >> 2;      // 0..15
  const int m0 = (mg * 8 + xcd) * 64;  // mg*8+xcd covers 0..127 bijectively
  const int n0 = n_tile * 128;

  const int t = threadIdx.x;
  const int lane = t & 63;
  const int w = t >> 6;
  const int wr = w & 1;   // 2 row-groups of 32
  const int wc = w >> 1;  // 2 col-groups of 64
  const int lrow = lane & 15;
  const int quad = lane >> 4;

  // A staging: 512 slots of 16B; slot s=i*256+t -> row s>>3, phys chunk s&7.
  const int aoff = ((t & 7) ^ ((t >> 3) & 7)) * 4;  // f32 col, inverse swizzle
  // B staging: 512 slots; slot s=i*256+t -> row s>>2, phys chunk s&3.
  const int boff = ((t & 3) ^ ((t >> 3) & 3)) * 8;  // bf16 col, inverse swizzle
  const float* ag = A + (size_t)(m0 + (t >> 3)) * K + aoff;
  const bf16_t* bg = Bt + (size_t)(n0 + (t >> 2)) * K + boff;

  auto stage = [&](int it, int buf) {
    const int kc = it * 32;
#pragma unroll
    for (int i = 0; i < 2; ++i)
      gload_lds16(ag + (size_t)(i * 32) * K + kc, &As[buf][(i * 256 + t) * 4]);
#pragma unroll
    for (int i = 0; i < 2; ++i)
      gload_lds16(bg + (size_t)(i * 64) * K + kc, &Bs[buf][(i * 256 + t) * 8]);
  };

  const int apc0 = ((quad * 2) ^ (lrow & 7)) * 4;
  const int apc1 = (((quad * 2) ^ (lrow & 7)) ^ 1) * 4;
  const int bpc = (quad ^ ((lrow >> 1) & 3)) * 8;

  f32x4 acc[2][4] = {};

  auto compute = [&](int buf) {
    bf16x8 af[2], bfr[4];
#pragma unroll
    for (int ii = 0; ii < 2; ++ii) {
      const int rb = (wr * 32 + ii * 16 + lrow) * 32;
      f32x4 a0 = *(const f32x4*)&As[buf][rb + apc0];
      f32x4 a1 = *(const f32x4*)&As[buf][rb + apc1];
#pragma unroll
      for (int z = 0; z < 4; ++z) {
        af[ii][z] = (bf16_t)a0[z];
        af[ii][z + 4] = (bf16_t)a1[z];
      }
    }
#pragma unroll
    for (int jj = 0; jj < 4; ++jj)
      bfr[jj] = *(const bf16x8*)&Bs[buf][(wc * 64 + jj * 16 + lrow) * 32 + bpc];
#pragma unroll
    for (int ii = 0; ii < 2; ++ii)
#pragma unroll
      for (int jj = 0; jj < 4; ++jj)
        acc[ii][jj] =
            __builtin_amdgcn_mfma_f32_16x16x32_bf16(af[ii], bfr[jj], acc[ii][jj], 0, 0, 0);
  };

  // Pre-load bias (oldest vmem ops; drained by the first counted wait, so the
  // stage ledger below is exact afterwards).
  float bjv[4];
#pragma unroll
  for (int jj = 0; jj < 4; ++jj) bjv[jj] = bias[n0 + wc * 64 + jj * 16 + lrow];

  // prologue: 3 stages in flight (12 DMAs/wave + 4 bias loads)
  stage(0, 0);
  stage(1, 1);
  stage(2, 2);

#pragma unroll 1
  for (int it = 0; it < NIT; ++it) {
    if (it < NIT - 2) {
      asm volatile("s_waitcnt vmcnt(8)" ::: "memory");
    } else if (it == NIT - 2) {
      asm volatile("s_waitcnt vmcnt(4)" ::: "memory");
    } else {
      asm volatile("s_waitcnt vmcnt(0)" ::: "memory");
    }
    asm volatile("s_waitcnt lgkmcnt(0)" ::: "memory");
    asm volatile("s_barrier" ::: "memory");
    if (it + 3 < NIT) stage(it + 3, (it + 3) & 3);
    compute(it & 3);
  }

#pragma unroll
  for (int ii = 0; ii < 2; ++ii)
#pragma unroll
    for (int jj = 0; jj < 4; ++jj) {
      const int col = n0 + wc * 64 + jj * 16 + lrow;
#pragma unroll
      for (int r = 0; r < 4; ++r) {
        const int row = m0 + wr * 32 + ii * 16 + quad * 4 + r;
        float v = acc[ii][jj][r] + bjv[jj];
        out[(size_t)row * DIM + col] = v > 0.0f ? v : 0.0f;
      }
    }
}

extern "C" void kernel_launch(void* const* d_in, const int* in_sizes, int n_in,
                              void* d_out, int out_size, void* d_ws, size_t ws_size,
                              hipStream_t stream) {
  const float* x = (const float*)d_in[0];    // [8192,512]
  const float* adj = (const float*)d_in[1];  // [8192,8192]
  const float* W = (const float*)d_in[2];    // [512,512]
  const float* b = (const float*)d_in[3];    // [512]
  float* out = (float*)d_out;

  // ws: Yt [512][8192] bf16 = 8 MB
  bf16_t* Yt = (bf16_t*)d_ws;

  // reassociation: out = relu(adj @ (x @ W^T) + b)
  k_yw<<<dim3(256), 256, 0, stream>>>(x, W, Yt);
  k_main<<<dim3(512), 256, 0, stream>>>(adj, Yt, b, out);
}

// Round 4
// 577.947 us; speedup vs baseline: 1.0053x; 1.0053x over previous
//
#include <hip/hip_runtime.h>
#include <stdint.h>

typedef __bf16 bf16_t;
typedef bf16_t bf16x8 __attribute__((ext_vector_type(8)));
typedef float f32x4 __attribute__((ext_vector_type(4)));

#define N_NODES 8192
#define DIM 512

typedef __attribute__((address_space(1))) void as1_void;
typedef __attribute__((address_space(3))) void as3_void;

// async global -> LDS, 16B per lane. LDS dest = wave-uniform base + lane*16.
__device__ __forceinline__ void gload_lds16(const void* g, void* l) {
  __builtin_amdgcn_global_load_lds((as1_void*)g, (as3_void*)l, 16, 0, 0);
}

// ============================================================================
// k_yw: Yt[n,k] = sum_d W[n,d] * x[k,d]   (Yt = (x @ W^T)^T, [512][8192] bf16)
// 128(n) x 128(k) tile, BK=32, 4 waves (2x2), wave-tile 64x64, acc[4][4].
// fp32 operands staged via global_load_lds, XOR swizzle, cvt->bf16 at read.
// Conservative __syncthreads double-buffer loop (NIT=16). Verified r3.
// ============================================================================
__global__ __launch_bounds__(256) void k_yw(const float* __restrict__ x,
                                            const float* __restrict__ W,
                                            bf16_t* __restrict__ Yt) {
  constexpr int NIT = DIM / 32;  // 16
  __shared__ float As[2][128 * 32];
  __shared__ float Bs[2][128 * 32];

  const int b = blockIdx.x;
  const int n0 = (b & 3) * 128;
  const int k0 = (b >> 2) * 128;

  const int t = threadIdx.x;
  const int lane = t & 63;
  const int w = t >> 6;
  const int wr = w & 1;
  const int wc = w >> 1;
  const int lrow = lane & 15;
  const int quad = lane >> 4;

  const int srow = t >> 3;
  const int aoff = ((t & 7) ^ (srow & 7)) * 4;
  const float* ag = W + (size_t)(n0 + srow) * DIM + aoff;
  const float* bg = x + (size_t)(k0 + srow) * DIM + aoff;

  auto stage = [&](int it, int buf) {
    const int kc = it * 32;
#pragma unroll
    for (int i = 0; i < 4; ++i) {
      gload_lds16(ag + (size_t)(i * 32) * DIM + kc, &As[buf][(i * 256 + t) * 4]);
      gload_lds16(bg + (size_t)(i * 32) * DIM + kc, &Bs[buf][(i * 256 + t) * 4]);
    }
  };

  const int apc0 = ((quad * 2) ^ (lrow & 7)) * 4;
  const int apc1 = (((quad * 2) ^ (lrow & 7)) ^ 1) * 4;

  f32x4 acc[4][4] = {};

  auto compute = [&](int buf) {
    bf16x8 af[4], bfr[4];
#pragma unroll
    for (int ii = 0; ii < 4; ++ii) {
      const int rb = (wr * 64 + ii * 16 + lrow) * 32;
      f32x4 a0 = *(const f32x4*)&As[buf][rb + apc0];
      f32x4 a1 = *(const f32x4*)&As[buf][rb + apc1];
#pragma unroll
      for (int z = 0; z < 4; ++z) {
        af[ii][z] = (bf16_t)a0[z];
        af[ii][z + 4] = (bf16_t)a1[z];
      }
    }
#pragma unroll
    for (int jj = 0; jj < 4; ++jj) {
      const int rb = (wc * 64 + jj * 16 + lrow) * 32;
      f32x4 b0 = *(const f32x4*)&Bs[buf][rb + apc0];
      f32x4 b1 = *(const f32x4*)&Bs[buf][rb + apc1];
#pragma unroll
      for (int z = 0; z < 4; ++z) {
        bfr[jj][z] = (bf16_t)b0[z];
        bfr[jj][z + 4] = (bf16_t)b1[z];
      }
    }
#pragma unroll
    for (int ii = 0; ii < 4; ++ii)
#pragma unroll
      for (int jj = 0; jj < 4; ++jj)
        acc[ii][jj] =
            __builtin_amdgcn_mfma_f32_16x16x32_bf16(af[ii], bfr[jj], acc[ii][jj], 0, 0, 0);
  };

  stage(0, 0);
  __syncthreads();
  int cur = 0;
#pragma unroll 1
  for (int it = 0; it < NIT; ++it) {
    if (it + 1 < NIT) stage(it + 1, cur ^ 1);
    compute(cur);
    __syncthreads();
    cur ^= 1;
  }

#pragma unroll
  for (int ii = 0; ii < 4; ++ii)
#pragma unroll
    for (int jj = 0; jj < 4; ++jj) {
      const int col = k0 + wc * 64 + jj * 16 + lrow;
#pragma unroll
      for (int r = 0; r < 4; ++r) {
        const int row = n0 + wr * 64 + ii * 16 + quad * 4 + r;
        Yt[(size_t)row * N_NODES + col] = (bf16_t)acc[ii][jj][r];
      }
    }
}

// ============================================================================
// k_main: out = relu(adj @ Y + b)
// A = adj f32, staged to LDS via global_load_lds (XOR swizzle), cvt at read.
// B = Yt bf16, L2-resident -> fragments loaded DIRECTLY from global into
// registers, double-buffered one iteration ahead (no LDS for B at all).
// 128x128 tile, BK=32, NIT=256, 4 waves (2x2), wave-tile 64x64, acc[4][4].
// Counted-vmcnt pipeline (verified r3): per wave/iter 4 A-DMAs + 4 B-loads,
// B issued BEFORE the A stage. Top-of-iter outstanding = A(it..it+2)+B(it)=16
// -> vmcnt(12) drains exactly A(it); tail 8 / 4. lgkmcnt(0)+s_barrier (asm,
// memory clobber) orders buffer reuse. LDS = 4 x 16 KB = 64 KB, grid 256
// (1 block/CU). XCD map: n-slice fixed per XCD (B slice 2 MB L2-resident),
// bijective: m_tile=((b>>3)<<1)|(b&1), n_tile=(b>>1)&3.
// ============================================================================
__global__ __launch_bounds__(256) void k_main(const float* __restrict__ A,
                                              const bf16_t* __restrict__ Bt,
                                              const float* __restrict__ bias,
                                              float* __restrict__ out) {
  constexpr int K = N_NODES;
  constexpr int NIT = K / 32;  // 256
  __shared__ float As[4][128 * 32];  // 64 KB

  const int b = blockIdx.x;
  const int m0 = (((b >> 3) << 1) | (b & 1)) * 128;
  const int n0 = ((b >> 1) & 3) * 128;

  const int t = threadIdx.x;
  const int lane = t & 63;
  const int w = t >> 6;
  const int wr = w & 1;
  const int wc = w >> 1;
  const int lrow = lane & 15;
  const int quad = lane >> 4;

  // A staging: 1024 slots of 16B; slot s=i*256+t -> row s>>3, phys chunk s&7.
  const int aoff = ((t & 7) ^ ((t >> 3) & 7)) * 4;  // inverse swizzle
  const float* ag = A + (size_t)(m0 + (t >> 3)) * K + aoff;

  auto stage = [&](int it, int buf) {
    const int kc = it * 32;
#pragma unroll
    for (int i = 0; i < 4; ++i)
      gload_lds16(ag + (size_t)(i * 32) * K + kc, &As[buf][(i * 256 + t) * 4]);
  };

  const int apc0 = ((quad * 2) ^ (lrow & 7)) * 4;
  const int apc1 = (((quad * 2) ^ (lrow & 7)) ^ 1) * 4;

  // B fragment source rows (per-thread constants)
  const bf16_t* bsrc[4];
#pragma unroll
  for (int jj = 0; jj < 4; ++jj)
    bsrc[jj] = Bt + (size_t)(n0 + wc * 64 + jj * 16 + lrow) * K + quad * 8;

  bf16x8 bA[4], bB[4];
  auto loadB = [&](int it, bf16x8* dst) {
    const int kc = it * 32;
#pragma unroll
    for (int jj = 0; jj < 4; ++jj) dst[jj] = *(const bf16x8*)(bsrc[jj] + kc);
  };

  f32x4 acc[4][4] = {};

  auto compute = [&](int buf, const bf16x8* bfr) {
    bf16x8 af[4];
#pragma unroll
    for (int ii = 0; ii < 4; ++ii) {
      const int rb = (wr * 64 + ii * 16 + lrow) * 32;
      f32x4 a0 = *(const f32x4*)&As[buf][rb + apc0];
      f32x4 a1 = *(const f32x4*)&As[buf][rb + apc1];
#pragma unroll
      for (int z = 0; z < 4; ++z) {
        af[ii][z] = (bf16_t)a0[z];
        af[ii][z + 4] = (bf16_t)a1[z];
      }
    }
#pragma unroll
    for (int ii = 0; ii < 4; ++ii)
#pragma unroll
      for (int jj = 0; jj < 4; ++jj)
        acc[ii][jj] =
            __builtin_amdgcn_mfma_f32_16x16x32_bf16(af[ii], bfr[jj], acc[ii][jj], 0, 0, 0);
  };

  auto syncit = [&](int it) {
    if (it < NIT - 2) {
      asm volatile("s_waitcnt vmcnt(12)" ::: "memory");
    } else if (it == NIT - 2) {
      asm volatile("s_waitcnt vmcnt(8)" ::: "memory");
    } else {
      asm volatile("s_waitcnt vmcnt(4)" ::: "memory");
    }
    asm volatile("s_waitcnt lgkmcnt(0)" ::: "memory");
    asm volatile("s_barrier" ::: "memory");
  };

  // prologue: 3 A-stages then B(0): queue = A0 A1 A2 B0 (16 outstanding/wave)
  stage(0, 0);
  stage(1, 1);
  stage(2, 2);
  loadB(0, bA);

#pragma unroll 1
  for (int it = 0; it < NIT; it += 2) {
    syncit(it);
    loadB(it + 1, bB);  // it+1 <= NIT-1 always (NIT even)
    if (it + 3 < NIT) stage(it + 3, (it + 3) & 3);
    compute(it & 3, bA);

    syncit(it + 1);
    if (it + 2 < NIT) loadB(it + 2, bA);
    if (it + 4 < NIT) stage(it + 4, (it + 4) & 3);
    compute((it + 1) & 3, bB);
  }

#pragma unroll
  for (int ii = 0; ii < 4; ++ii)
#pragma unroll
    for (int jj = 0; jj < 4; ++jj) {
      const int col = n0 + wc * 64 + jj * 16 + lrow;
      const float bj = bias[col];
#pragma unroll
      for (int r = 0; r < 4; ++r) {
        const int row = m0 + wr * 64 + ii * 16 + quad * 4 + r;
        float v = acc[ii][jj][r] + bj;
        out[(size_t)row * DIM + col] = v > 0.0f ? v : 0.0f;
      }
    }
}

extern "C" void kernel_launch(void* const* d_in, const int* in_sizes, int n_in,
                              void* d_out, int out_size, void* d_ws, size_t ws_size,
                              hipStream_t stream) {
  const float* x = (const float*)d_in[0];    // [8192,512]
  const float* adj = (const float*)d_in[1];  // [8192,8192]
  const float* W = (const float*)d_in[2];    // [512,512]
  const float* b = (const float*)d_in[3];    // [512]
  float* out = (float*)d_out;

  // ws: Yt [512][8192] bf16 = 8 MB
  bf16_t* Yt = (bf16_t*)d_ws;

  // reassociation: out = relu(adj @ (x @ W^T) + b)
  k_yw<<<dim3(256), 256, 0, stream>>>(x, W, Yt);
  k_main<<<dim3(256), 256, 0, stream>>>(adj, Yt, b, out);
}

// Round 5
// 514.753 us; speedup vs baseline: 1.1287x; 1.1228x over previous
//
#include <hip/hip_runtime.h>
#include <stdint.h>

typedef __bf16 bf16_t;
typedef bf16_t bf16x8 __attribute__((ext_vector_type(8)));
typedef float f32x4 __attribute__((ext_vector_type(4)));

#define N_NODES 8192
#define DIM 512

typedef __attribute__((address_space(1))) void as1_void;
typedef __attribute__((address_space(3))) void as3_void;

// async global -> LDS, 16B per lane. LDS dest = wave-uniform base + lane*16.
__device__ __forceinline__ void gload_lds16(const void* g, void* l) {
  __builtin_amdgcn_global_load_lds((as1_void*)g, (as3_void*)l, 16, 0, 0);
}

// ============================================================================
// k_yw: Yt[n,k] = sum_d W[n,d] * x[k,d]   (Yt = (x @ W^T)^T, [512][8192] bf16)
// Verified r3/r4. 128x128 tile, BK=32, 4 waves, acc[4][4], __syncthreads loop.
// ============================================================================
__global__ __launch_bounds__(256) void k_yw(const float* __restrict__ x,
                                            const float* __restrict__ W,
                                            bf16_t* __restrict__ Yt) {
  constexpr int NIT = DIM / 32;  // 16
  __shared__ float As[2][128 * 32];
  __shared__ float Bs[2][128 * 32];

  const int b = blockIdx.x;
  const int n0 = (b & 3) * 128;
  const int k0 = (b >> 2) * 128;

  const int t = threadIdx.x;
  const int lane = t & 63;
  const int w = t >> 6;
  const int wr = w & 1;
  const int wc = w >> 1;
  const int lrow = lane & 15;
  const int quad = lane >> 4;

  const int srow = t >> 3;
  const int aoff = ((t & 7) ^ (srow & 7)) * 4;
  const float* ag = W + (size_t)(n0 + srow) * DIM + aoff;
  const float* bg = x + (size_t)(k0 + srow) * DIM + aoff;

  auto stage = [&](int it, int buf) {
    const int kc = it * 32;
#pragma unroll
    for (int i = 0; i < 4; ++i) {
      gload_lds16(ag + (size_t)(i * 32) * DIM + kc, &As[buf][(i * 256 + t) * 4]);
      gload_lds16(bg + (size_t)(i * 32) * DIM + kc, &Bs[buf][(i * 256 + t) * 4]);
    }
  };

  const int apc0 = ((quad * 2) ^ (lrow & 7)) * 4;
  const int apc1 = (((quad * 2) ^ (lrow & 7)) ^ 1) * 4;

  f32x4 acc[4][4] = {};

  auto compute = [&](int buf) {
    bf16x8 af[4], bfr[4];
#pragma unroll
    for (int ii = 0; ii < 4; ++ii) {
      const int rb = (wr * 64 + ii * 16 + lrow) * 32;
      f32x4 a0 = *(const f32x4*)&As[buf][rb + apc0];
      f32x4 a1 = *(const f32x4*)&As[buf][rb + apc1];
#pragma unroll
      for (int z = 0; z < 4; ++z) {
        af[ii][z] = (bf16_t)a0[z];
        af[ii][z + 4] = (bf16_t)a1[z];
      }
    }
#pragma unroll
    for (int jj = 0; jj < 4; ++jj) {
      const int rb = (wc * 64 + jj * 16 + lrow) * 32;
      f32x4 b0 = *(const f32x4*)&Bs[buf][rb + apc0];
      f32x4 b1 = *(const f32x4*)&Bs[buf][rb + apc1];
#pragma unroll
      for (int z = 0; z < 4; ++z) {
        bfr[jj][z] = (bf16_t)b0[z];
        bfr[jj][z + 4] = (bf16_t)b1[z];
      }
    }
#pragma unroll
    for (int ii = 0; ii < 4; ++ii)
#pragma unroll
      for (int jj = 0; jj < 4; ++jj)
        acc[ii][jj] =
            __builtin_amdgcn_mfma_f32_16x16x32_bf16(af[ii], bfr[jj], acc[ii][jj], 0, 0, 0);
  };

  stage(0, 0);
  __syncthreads();
  int cur = 0;
#pragma unroll 1
  for (int it = 0; it < NIT; ++it) {
    if (it + 1 < NIT) stage(it + 1, cur ^ 1);
    compute(cur);
    __syncthreads();
    cur ^= 1;
  }

#pragma unroll
  for (int ii = 0; ii < 4; ++ii)
#pragma unroll
    for (int jj = 0; jj < 4; ++jj) {
      const int col = k0 + wc * 64 + jj * 16 + lrow;
#pragma unroll
      for (int r = 0; r < 4; ++r) {
        const int row = n0 + wr * 64 + ii * 16 + quad * 4 + r;
        Yt[(size_t)row * N_NODES + col] = (bf16_t)acc[ii][jj][r];
      }
    }
}

// ============================================================================
// k_main: P[ks] = adj[:, ks*2048:(ks+1)*2048] @ Y[ks-chunk, :]   (f32 partial)
// m97 structure at 3 blocks/CU: 128x128 tile, BK=32, NIT=64, 4 waves (2x2),
// wave-tile 64x64, acc[4][4]. A f32 + B bf16 staged via global_load_lds with
// the r3/r4-verified XOR swizzle; plain __syncthreads 2-buffer loop (inter-
// block overlap hides the barrier drain, per m97/m114). LDS = 48 KB -> 3
// blocks/CU; grid 1024 (64 m x 4 n x 4 ks).
// Block decode b = m*16 + n*4 + ks -> XCD (b&7) is a pure fn of (n,ks):
// B slice (512 KB) stays L2-resident; adj chunk fetched by 2 XCDs only.
// ============================================================================
__global__ __launch_bounds__(256) void k_main(const float* __restrict__ A,
                                              const bf16_t* __restrict__ Bt,
                                              float* __restrict__ P) {
  constexpr int K = N_NODES;
  constexpr int KC = 2048;       // K per split
  constexpr int NIT = KC / 32;   // 64
  __shared__ float As[2][128 * 32];   // 32 KB
  __shared__ bf16_t Bs[2][128 * 32];  // 16 KB

  const int b = blockIdx.x;
  const int ks = b & 3;
  const int n0 = ((b >> 2) & 3) * 128;
  const int m0 = (b >> 4) * 128;
  const int kbase = ks * KC;

  const int t = threadIdx.x;
  const int lane = t & 63;
  const int w = t >> 6;
  const int wr = w & 1;
  const int wc = w >> 1;
  const int lrow = lane & 15;
  const int quad = lane >> 4;

  // A staging: 1024 slots of 16B; slot s=i*256+t -> row s>>3, phys chunk s&7.
  const int aoff = ((t & 7) ^ ((t >> 3) & 7)) * 4;  // f32 col, inverse swizzle
  // B staging: 512 slots; slot s=i*256+t -> row s>>2, phys chunk s&3.
  const int boff = ((t & 3) ^ ((t >> 3) & 3)) * 8;  // bf16 col, inverse swizzle
  const float* ag = A + (size_t)(m0 + (t >> 3)) * K + kbase + aoff;
  const bf16_t* bg = Bt + (size_t)(n0 + (t >> 2)) * K + kbase + boff;

  auto stage = [&](int it, int buf) {
    const int kc = it * 32;
#pragma unroll
    for (int i = 0; i < 4; ++i)
      gload_lds16(ag + (size_t)(i * 32) * K + kc, &As[buf][(i * 256 + t) * 4]);
#pragma unroll
    for (int i = 0; i < 2; ++i)
      gload_lds16(bg + (size_t)(i * 64) * K + kc, &Bs[buf][(i * 256 + t) * 8]);
  };

  const int apc0 = ((quad * 2) ^ (lrow & 7)) * 4;
  const int apc1 = (((quad * 2) ^ (lrow & 7)) ^ 1) * 4;
  const int bpc = (quad ^ ((lrow >> 1) & 3)) * 8;

  f32x4 acc[4][4] = {};

  auto compute = [&](int buf) {
    bf16x8 af[4], bfr[4];
#pragma unroll
    for (int ii = 0; ii < 4; ++ii) {
      const int rb = (wr * 64 + ii * 16 + lrow) * 32;
      f32x4 a0 = *(const f32x4*)&As[buf][rb + apc0];
      f32x4 a1 = *(const f32x4*)&As[buf][rb + apc1];
#pragma unroll
      for (int z = 0; z < 4; ++z) {
        af[ii][z] = (bf16_t)a0[z];
        af[ii][z + 4] = (bf16_t)a1[z];
      }
    }
#pragma unroll
    for (int jj = 0; jj < 4; ++jj)
      bfr[jj] = *(const bf16x8*)&Bs[buf][(wc * 64 + jj * 16 + lrow) * 32 + bpc];
#pragma unroll
    for (int ii = 0; ii < 4; ++ii)
#pragma unroll
      for (int jj = 0; jj < 4; ++jj)
        acc[ii][jj] =
            __builtin_amdgcn_mfma_f32_16x16x32_bf16(af[ii], bfr[jj], acc[ii][jj], 0, 0, 0);
  };

  stage(0, 0);
  __syncthreads();
  int cur = 0;
#pragma unroll 1
  for (int it = 0; it < NIT; ++it) {
    if (it + 1 < NIT) stage(it + 1, cur ^ 1);
    compute(cur);
    __syncthreads();
    cur ^= 1;
  }

  float* Pp = P + (size_t)ks * N_NODES * DIM;
#pragma unroll
  for (int ii = 0; ii < 4; ++ii)
#pragma unroll
    for (int jj = 0; jj < 4; ++jj) {
      const int col = n0 + wc * 64 + jj * 16 + lrow;
#pragma unroll
      for (int r = 0; r < 4; ++r) {
        const int row = m0 + wr * 64 + ii * 16 + quad * 4 + r;
        Pp[(size_t)row * DIM + col] = acc[ii][jj][r];
      }
    }
}

// ============================================================================
// k_combine: out = relu(P0 + P1 + P2 + P3 + bias), vectorized f32x4.
// ============================================================================
__global__ __launch_bounds__(256) void k_combine(const float* __restrict__ P,
                                                 const float* __restrict__ bias,
                                                 float* __restrict__ out) {
  constexpr size_t PS = (size_t)N_NODES * DIM;
  constexpr int NV = N_NODES * DIM / 4;  // 1M vec4
  const int stride = gridDim.x * blockDim.x;
  for (int v = blockIdx.x * blockDim.x + threadIdx.x; v < NV; v += stride) {
    f32x4 s0 = ((const f32x4*)P)[v];
    f32x4 s1 = ((const f32x4*)(P + PS))[v];
    f32x4 s2 = ((const f32x4*)(P + 2 * PS))[v];
    f32x4 s3 = ((const f32x4*)(P + 3 * PS))[v];
    f32x4 bv = *(const f32x4*)&bias[(v & 127) * 4];
    f32x4 r;
#pragma unroll
    for (int z = 0; z < 4; ++z) {
      float tv = s0[z] + s1[z] + s2[z] + s3[z] + bv[z];
      r[z] = tv > 0.0f ? tv : 0.0f;
    }
    ((f32x4*)out)[v] = r;
  }
}

extern "C" void kernel_launch(void* const* d_in, const int* in_sizes, int n_in,
                              void* d_out, int out_size, void* d_ws, size_t ws_size,
                              hipStream_t stream) {
  const float* x = (const float*)d_in[0];    // [8192,512]
  const float* adj = (const float*)d_in[1];  // [8192,8192]
  const float* W = (const float*)d_in[2];    // [512,512]
  const float* b = (const float*)d_in[3];    // [512]
  float* out = (float*)d_out;

  // ws: Yt [512][8192] bf16 = 8 MB | P [4][8192][512] f32 = 64 MB  (72 MB)
  bf16_t* Yt = (bf16_t*)d_ws;
  float* P = (float*)(Yt + (size_t)DIM * N_NODES);

  // out = relu(adj @ (x @ W^T) + b)
  k_yw<<<dim3(256), 256, 0, stream>>>(x, W, Yt);
  k_main<<<dim3(1024), 256, 0, stream>>>(adj, Yt, P);
  k_combine<<<dim3(2048), 256, 0, stream>>>(P, b, out);
}

// Round 6
// 472.151 us; speedup vs baseline: 1.2306x; 1.0902x over previous
//
#include <hip/hip_runtime.h>
#include <stdint.h>

typedef __bf16 bf16_t;
typedef bf16_t bf16x8 __attribute__((ext_vector_type(8)));
typedef float f32x4 __attribute__((ext_vector_type(4)));

#define N_NODES 8192
#define DIM 512

typedef __attribute__((address_space(1))) void as1_void;
typedef __attribute__((address_space(3))) void as3_void;

// async global -> LDS, 16B per lane. LDS dest = wave-uniform base + lane*16.
__device__ __forceinline__ void gload_lds16(const void* g, void* l) {
  __builtin_amdgcn_global_load_lds((as1_void*)g, (as3_void*)l, 16, 0, 0);
}

// ============================================================================
// k_yw: Yt[n,k] = sum_d W[n,d] * x[k,d]   (Yt = (x @ W^T)^T, [512][8192] bf16)
// Verified r3-r5. 128x128 tile, BK=32, 4 waves, acc[4][4], __syncthreads loop.
// ============================================================================
__global__ __launch_bounds__(256) void k_yw(const float* __restrict__ x,
                                            const float* __restrict__ W,
                                            bf16_t* __restrict__ Yt) {
  constexpr int NIT = DIM / 32;  // 16
  __shared__ float As[2][128 * 32];
  __shared__ float Bs[2][128 * 32];

  const int b = blockIdx.x;
  const int n0 = (b & 3) * 128;
  const int k0 = (b >> 2) * 128;

  const int t = threadIdx.x;
  const int lane = t & 63;
  const int w = t >> 6;
  const int wr = w & 1;
  const int wc = w >> 1;
  const int lrow = lane & 15;
  const int quad = lane >> 4;

  const int srow = t >> 3;
  const int aoff = ((t & 7) ^ (srow & 7)) * 4;
  const float* ag = W + (size_t)(n0 + srow) * DIM + aoff;
  const float* bg = x + (size_t)(k0 + srow) * DIM + aoff;

  auto stage = [&](int it, int buf) {
    const int kc = it * 32;
#pragma unroll
    for (int i = 0; i < 4; ++i) {
      gload_lds16(ag + (size_t)(i * 32) * DIM + kc, &As[buf][(i * 256 + t) * 4]);
      gload_lds16(bg + (size_t)(i * 32) * DIM + kc, &Bs[buf][(i * 256 + t) * 4]);
    }
  };

  const int apc0 = ((quad * 2) ^ (lrow & 7)) * 4;
  const int apc1 = (((quad * 2) ^ (lrow & 7)) ^ 1) * 4;

  f32x4 acc[4][4] = {};

  auto compute = [&](int buf) {
    bf16x8 af[4], bfr[4];
#pragma unroll
    for (int ii = 0; ii < 4; ++ii) {
      const int rb = (wr * 64 + ii * 16 + lrow) * 32;
      f32x4 a0 = *(const f32x4*)&As[buf][rb + apc0];
      f32x4 a1 = *(const f32x4*)&As[buf][rb + apc1];
#pragma unroll
      for (int z = 0; z < 4; ++z) {
        af[ii][z] = (bf16_t)a0[z];
        af[ii][z + 4] = (bf16_t)a1[z];
      }
    }
#pragma unroll
    for (int jj = 0; jj < 4; ++jj) {
      const int rb = (wc * 64 + jj * 16 + lrow) * 32;
      f32x4 b0 = *(const f32x4*)&Bs[buf][rb + apc0];
      f32x4 b1 = *(const f32x4*)&Bs[buf][rb + apc1];
#pragma unroll
      for (int z = 0; z < 4; ++z) {
        bfr[jj][z] = (bf16_t)b0[z];
        bfr[jj][z + 4] = (bf16_t)b1[z];
      }
    }
#pragma unroll
    for (int ii = 0; ii < 4; ++ii)
#pragma unroll
      for (int jj = 0; jj < 4; ++jj)
        acc[ii][jj] =
            __builtin_amdgcn_mfma_f32_16x16x32_bf16(af[ii], bfr[jj], acc[ii][jj], 0, 0, 0);
  };

  stage(0, 0);
  __syncthreads();
  int cur = 0;
#pragma unroll 1
  for (int it = 0; it < NIT; ++it) {
    if (it + 1 < NIT) stage(it + 1, cur ^ 1);
    compute(cur);
    __syncthreads();
    cur ^= 1;
  }

#pragma unroll
  for (int ii = 0; ii < 4; ++ii)
#pragma unroll
    for (int jj = 0; jj < 4; ++jj) {
      const int col = k0 + wc * 64 + jj * 16 + lrow;
#pragma unroll
      for (int r = 0; r < 4; ++r) {
        const int row = n0 + wr * 64 + ii * 16 + quad * 4 + r;
        Yt[(size_t)row * N_NODES + col] = (bf16_t)acc[ii][jj][r];
      }
    }
}

// ============================================================================
// k_main: P[ks] = adj[:, ks-chunk] @ Y[ks-chunk, :]   (f32 partial)
// FAT-TILE 2-phase: BM=128, BN=512 (full DIM), BK=32, 8 waves (512 thr),
// wave-tile 64x128, acc[4][8]. Per-iter compute (~32 MFMA + 16 ds_read_b128
// per wave, 2 waves/SIMD) ~ 1200+ cy >= HBM latency, so the verified 2-phase
// __syncthreads skeleton hides the staging latency (r3/r4/r5 failed because
// compute/iter was ~300 cy << latency). LDS = 96 KB -> 1 block/CU, grid 256
// (64 m-tiles x 4 ks). All staging/swizzle/fragment formulas identical to the
// r5-verified ones (A: 8-chunk f32 rows; B: 4-chunk bf16 rows).
// XCD decode b=m*4+ks: each XCD owns one ks -> B ks-slice (2 MB) L2-resident;
// adj element read by exactly one block (BN = full DIM).
// ============================================================================
__global__ __launch_bounds__(512, 2) void k_main(const float* __restrict__ A,
                                                 const bf16_t* __restrict__ Bt,
                                                 float* __restrict__ P) {
  constexpr int K = N_NODES;
  constexpr int KC = 2048;      // K per split (ksplit = 4)
  constexpr int NIT = KC / 32;  // 64
  __shared__ float As[2][128 * 32];   // 32 KB
  __shared__ bf16_t Bs[2][512 * 32];  // 64 KB

  const int b = blockIdx.x;
  const int ks = b & 3;
  const int m0 = (b >> 2) * 128;
  const int kbase = ks * KC;

  const int t = threadIdx.x;
  const int lane = t & 63;
  const int w = t >> 6;      // 0..7
  const int wr = w & 1;      // 2 row-groups of 64
  const int wc = w >> 1;     // 4 col-groups of 128
  const int lrow = lane & 15;
  const int quad = lane >> 4;

  // A staging: 1024 slots of 16B; slot s=i*512+t -> row s>>3 = i*64+(t>>3),
  // phys chunk s&7 = t&7. Inverse swizzle on source ((row&7) = (t>>3)&7,
  // i-invariant since 64 = 0 mod 8).
  const int aoff = ((t & 7) ^ ((t >> 3) & 7)) * 4;
  // B staging: 2048 slots; slot s=i*512+t -> row s>>2 = i*128+(t>>2),
  // phys chunk s&3 = t&3. Inverse swizzle ((row>>1)&3 = (t>>3)&3, i-invariant
  // since 128>>1 = 64 = 0 mod 4).
  const int boff = ((t & 3) ^ ((t >> 3) & 3)) * 8;
  const float* ag = A + (size_t)(m0 + (t >> 3)) * K + kbase + aoff;
  const bf16_t* bg = Bt + (size_t)(t >> 2) * K + kbase + boff;

  auto stage = [&](int it, int buf) {
    const int kc = it * 32;
#pragma unroll
    for (int i = 0; i < 2; ++i)  // A: 1024 slots = 512 thr x 2
      gload_lds16(ag + (size_t)(i * 64) * K + kc, &As[buf][(i * 512 + t) * 4]);
#pragma unroll
    for (int i = 0; i < 4; ++i)  // B: 2048 slots = 512 thr x 4
      gload_lds16(bg + (size_t)(i * 128) * K + kc, &Bs[buf][(i * 512 + t) * 8]);
  };

  // read-side swizzled offsets (r5-verified formulas)
  const int apc0 = ((quad * 2) ^ (lrow & 7)) * 4;
  const int apc1 = (((quad * 2) ^ (lrow & 7)) ^ 1) * 4;
  const int bpc = (quad ^ ((lrow >> 1) & 3)) * 8;

  f32x4 acc[4][8] = {};

  auto compute = [&](int buf) {
    bf16x8 af[4];
#pragma unroll
    for (int ii = 0; ii < 4; ++ii) {
      const int rb = (wr * 64 + ii * 16 + lrow) * 32;
      f32x4 a0 = *(const f32x4*)&As[buf][rb + apc0];
      f32x4 a1 = *(const f32x4*)&As[buf][rb + apc1];
#pragma unroll
      for (int z = 0; z < 4; ++z) {
        af[ii][z] = (bf16_t)a0[z];
        af[ii][z + 4] = (bf16_t)a1[z];
      }
    }
    bf16x8 bfr[8];
#pragma unroll
    for (int jj = 0; jj < 8; ++jj)
      bfr[jj] = *(const bf16x8*)&Bs[buf][(wc * 128 + jj * 16 + lrow) * 32 + bpc];
#pragma unroll
    for (int ii = 0; ii < 4; ++ii)
#pragma unroll
      for (int jj = 0; jj < 8; ++jj)
        acc[ii][jj] =
            __builtin_amdgcn_mfma_f32_16x16x32_bf16(af[ii], bfr[jj], acc[ii][jj], 0, 0, 0);
  };

  stage(0, 0);
  __syncthreads();
  int cur = 0;
#pragma unroll 1
  for (int it = 0; it < NIT; ++it) {
    if (it + 1 < NIT) stage(it + 1, cur ^ 1);
    compute(cur);
    __syncthreads();
    cur ^= 1;
  }

  float* Pp = P + (size_t)ks * N_NODES * DIM;
#pragma unroll
  for (int ii = 0; ii < 4; ++ii)
#pragma unroll
    for (int jj = 0; jj < 8; ++jj) {
      const int col = wc * 128 + jj * 16 + lrow;
#pragma unroll
      for (int r = 0; r < 4; ++r) {
        const int row = m0 + wr * 64 + ii * 16 + quad * 4 + r;
        Pp[(size_t)row * DIM + col] = acc[ii][jj][r];
      }
    }
}

// ============================================================================
// k_combine: out = relu(P0 + P1 + P2 + P3 + bias), vectorized f32x4. (r5 ok)
// ============================================================================
__global__ __launch_bounds__(256) void k_combine(const float* __restrict__ P,
                                                 const float* __restrict__ bias,
                                                 float* __restrict__ out) {
  constexpr size_t PS = (size_t)N_NODES * DIM;
  constexpr int NV = N_NODES * DIM / 4;  // 1M vec4
  const int stride = gridDim.x * blockDim.x;
  for (int v = blockIdx.x * blockDim.x + threadIdx.x; v < NV; v += stride) {
    f32x4 s0 = ((const f32x4*)P)[v];
    f32x4 s1 = ((const f32x4*)(P + PS))[v];
    f32x4 s2 = ((const f32x4*)(P + 2 * PS))[v];
    f32x4 s3 = ((const f32x4*)(P + 3 * PS))[v];
    f32x4 bv = *(const f32x4*)&bias[(v & 127) * 4];
    f32x4 r;
#pragma unroll
    for (int z = 0; z < 4; ++z) {
      float tv = s0[z] + s1[z] + s2[z] + s3[z] + bv[z];
      r[z] = tv > 0.0f ? tv : 0.0f;
    }
    ((f32x4*)out)[v] = r;
  }
}

extern "C" void kernel_launch(void* const* d_in, const int* in_sizes, int n_in,
                              void* d_out, int out_size, void* d_ws, size_t ws_size,
                              hipStream_t stream) {
  const float* x = (const float*)d_in[0];    // [8192,512]
  const float* adj = (const float*)d_in[1];  // [8192,8192]
  const float* W = (const float*)d_in[2];    // [512,512]
  const float* b = (const float*)d_in[3];    // [512]
  float* out = (float*)d_out;

  // ws: Yt [512][8192] bf16 = 8 MB | P [4][8192][512] f32 = 64 MB  (72 MB)
  bf16_t* Yt = (bf16_t*)d_ws;
  float* P = (float*)(Yt + (size_t)DIM * N_NODES);

  // out = relu(adj @ (x @ W^T) + b)
  k_yw<<<dim3(256), 256, 0, stream>>>(x, W, Yt);
  k_main<<<dim3(256), 512, 0, stream>>>(adj, Yt, P);
  k_combine<<<dim3(2048), 256, 0, stream>>>(P, b, out);
}